// Round 1
// 424.756 us; speedup vs baseline: 1.0299x; 1.0299x over previous
//
#include <hip/hip_runtime.h>

// Problem constants (from reference):
//   z:         (B=8, N=64, M=512, F=256) fp32
//   Mask:      (B, F) int
//   eta_fault: (15, 4) fp32
//   out[b,n,m,f] = e0 + e1 * sigmoid((z - e2) * e3),  eta = eta_fault[Mask[b,f]]
#define BB 8
#define NN 64
#define MM 512
#define FF 256

// clang ext-vector type so __builtin_nontemporal_load/store accept it
typedef float v4f __attribute__((ext_vector_type(4)));

// Each block: 256 threads = 4 waves. A wave (64 lanes x float4) covers one
// full f-row (256 floats). Block handles a 64-m chunk of one (b,n) slab:
// wave w does m = chunk + w + 4*i, i = 0..15. Each thread gathers its 4
// eta rows ONCE (registers), pre-folded into fma form, then streams z->out
// with non-temporal (nt) loads/stores: pure streaming, zero reuse, so skip
// L2/L3 allocation churn on both the read and write paths.
__global__ __launch_bounds__(256) void sigmoid_rt_kernel(
    const float* __restrict__ z,
    const int* __restrict__ mask,
    const float* __restrict__ eta,
    float* __restrict__ out)
{
    const int mchunks = MM / 64;               // 8
    int bid = blockIdx.x;
    int mc  = bid % mchunks;
    int bn  = bid / mchunks;
    int n   = bn % NN;
    int b   = bn / NN;

    int lane = threadIdx.x & 63;
    int wave = threadIdx.x >> 6;               // 0..3
    int f0   = lane << 2;                      // 4 consecutive f per thread

    // Gather eta params for f0..f0+3, fold into: u = k*z + q ; out = e1*s + e0
    // where s = 1/(1 + exp2(u)), k = -log2(e)*e3, q = -k*e2.
    float k[4], q[4], a0[4], a1[4];
    const int* mrow = mask + b * FF;
    const float LOG2E = 1.4426950408889634f;
#pragma unroll
    for (int j = 0; j < 4; ++j) {
        int idx = mrow[f0 + j];
        const float* er = eta + idx * 4;
        float e0 = er[0], e1 = er[1], e2 = er[2], e3 = er[3];
        k[j]  = -LOG2E * e3;
        q[j]  = LOG2E * e3 * e2;
        a0[j] = e0;
        a1[j] = e1;
    }

    size_t base = ((size_t)(b * NN + n) * MM + (size_t)mc * 64) * FF;
    const v4f* zp = (const v4f*)(z + base);
    v4f*       op = (v4f*)(out + base);
    const int row_f4 = FF / 4;                 // 64 float4 per m-row

#pragma unroll 4
    for (int i = 0; i < 16; ++i) {
        int m_local = wave + (i << 2);         // 0..63 within chunk
        int off = m_local * row_f4 + lane;
        v4f zv = __builtin_nontemporal_load(zp + off);
        v4f r;
        {
            float u = fmaf(k[0], zv.x, q[0]);
            float s = __builtin_amdgcn_rcpf(1.0f + __builtin_amdgcn_exp2f(u));
            r.x = fmaf(a1[0], s, a0[0]);
        }
        {
            float u = fmaf(k[1], zv.y, q[1]);
            float s = __builtin_amdgcn_rcpf(1.0f + __builtin_amdgcn_exp2f(u));
            r.y = fmaf(a1[1], s, a0[1]);
        }
        {
            float u = fmaf(k[2], zv.z, q[2]);
            float s = __builtin_amdgcn_rcpf(1.0f + __builtin_amdgcn_exp2f(u));
            r.z = fmaf(a1[2], s, a0[2]);
        }
        {
            float u = fmaf(k[3], zv.w, q[3]);
            float s = __builtin_amdgcn_rcpf(1.0f + __builtin_amdgcn_exp2f(u));
            r.w = fmaf(a1[3], s, a0[3]);
        }
        __builtin_nontemporal_store(r, op + off);
    }
}

extern "C" void kernel_launch(void* const* d_in, const int* in_sizes, int n_in,
                              void* d_out, int out_size, void* d_ws, size_t ws_size,
                              hipStream_t stream) {
    const float* z    = (const float*)d_in[0];
    const int*   mask = (const int*)d_in[1];
    const float* eta  = (const float*)d_in[2];
    float*       out  = (float*)d_out;

    dim3 grid(BB * NN * (MM / 64));            // 4096 blocks
    dim3 block(256);
    sigmoid_rt_kernel<<<grid, block, 0, stream>>>(z, mask, eta, out);
}